// Round 1
// baseline (299.724 us; speedup 1.0000x reference)
//
#include <hip/hip_runtime.h>

#define BB    8
#define LQN   2048
#define LKVN  2048
#define DQ    128
#define DVN   128
#define QT    64
#define KT    128
#define STR   136   // LDS row stride in bf16 elements (16B-aligned, bank-optimal for b128)

typedef short short8 __attribute__((ext_vector_type(8)));
typedef float f32x4  __attribute__((ext_vector_type(4)));

__device__ __forceinline__ short f2bf(float f) {
  unsigned u = __builtin_bit_cast(unsigned, f);
  u += 0x7fffu + ((u >> 16) & 1u);   // round-to-nearest-even
  return (short)(u >> 16);
}

// V (B, LKV, DV) fp32  ->  Vt (B, DV, LKV) bf16   (so PV B-frags read contiguous)
__global__ __launch_bounds__(256) void vtrans_kernel(const float* __restrict__ V,
                                                     short* __restrict__ Vt) {
  __shared__ float tile[128][33];
  const int kv0 = blockIdx.x * 128;
  const int dv0 = blockIdx.y * 32;
  const int b   = blockIdx.z;
  const int tid = threadIdx.x;
  const float* src = V + ((size_t)b * LKVN + kv0) * DVN + dv0;
#pragma unroll
  for (int it = 0; it < 4; ++it) {
    int idx = it * 256 + tid;
    int r = idx >> 3, c4 = idx & 7;
    float4 v = *(const float4*)(src + (size_t)r * DVN + c4 * 4);
    tile[r][c4 * 4 + 0] = v.x;
    tile[r][c4 * 4 + 1] = v.y;
    tile[r][c4 * 4 + 2] = v.z;
    tile[r][c4 * 4 + 3] = v.w;
  }
  __syncthreads();
  short* dst = Vt + ((size_t)b * DVN + dv0) * LKVN + kv0;
#pragma unroll
  for (int it = 0; it < 2; ++it) {
    int idx = it * 256 + tid;
    int row = idx >> 4, ch = idx & 15;
    short8 o;
#pragma unroll
    for (int j = 0; j < 8; ++j) o[j] = f2bf(tile[ch * 8 + j][row]);
    *(short8*)(dst + (size_t)row * LKVN + ch * 8) = o;
  }
}

// One block = 64 Q-rows of one batch. Phase 1: S = scale*Q K^T via MFMA, raw scores
// -> weights region (scratch), online m/l in registers. Phase 2: P = exp(s-m)/l
// (final weights) + ctx = P V via MFMA with LDS-staged V^T tiles.
__global__ __launch_bounds__(256) void attn_kernel(const float* __restrict__ Q,
                                                   const float* __restrict__ K,
                                                   const short* __restrict__ Vt,
                                                   float* __restrict__ W,
                                                   float* __restrict__ O) {
  __shared__ __align__(16) short q_lds[QT][STR];
  __shared__ __align__(16) short kv_lds[KT][STR];
  __shared__ float stats_m[QT];
  __shared__ float stats_l[QT];

  const int tid  = threadIdx.x;
  const int wv   = tid >> 6;
  const int lane = tid & 63;
  const int n    = lane & 15;   // MFMA: A-row / B-col / C-col index
  const int qd   = lane >> 4;   // MFMA quad: k-chunk (inputs), row-group (C/D)
  const int q0   = blockIdx.x * QT;
  const int b    = blockIdx.y;

  // ---- stage Q tile: fp32 -> bf16 LDS ----
  {
    const float* Qp = Q + ((size_t)b * LQN + q0) * DQ;
#pragma unroll
    for (int it = 0; it < 8; ++it) {
      int idx = it * 256 + tid;
      int r = idx >> 5, c4 = idx & 31;
      float4 v = *(const float4*)(Qp + (size_t)r * DQ + c4 * 4);
      q_lds[r][c4 * 4 + 0] = f2bf(v.x);
      q_lds[r][c4 * 4 + 1] = f2bf(v.y);
      q_lds[r][c4 * 4 + 2] = f2bf(v.z);
      q_lds[r][c4 * 4 + 3] = f2bf(v.w);
    }
  }
  __syncthreads();

  // A-frags for this wave's 16 Q-rows: A[m=lane&15][k=qd*8+j], row = wv*16+m
  short8 af[4];
#pragma unroll
  for (int ks = 0; ks < 4; ++ks)
    af[ks] = *(const short8*)&q_lds[wv * 16 + n][ks * 32 + qd * 8];

  float m_run[4], l_run[4];
#pragma unroll
  for (int r = 0; r < 4; ++r) { m_run[r] = -1e30f; l_run[r] = 0.0f; }

  float* Wb = W + ((size_t)b * LQN + q0) * LKVN;
  const float scale = 0.08838834764831845f;  // 1/sqrt(128)

  // ---------------- phase 1 ----------------
  for (int kv0 = 0; kv0 < LKVN; kv0 += KT) {
    __syncthreads();  // WAR on kv_lds vs previous iteration's readers
    {
      const float* Kp = K + ((size_t)b * LKVN + kv0) * DQ;
#pragma unroll
      for (int it = 0; it < 16; ++it) {
        int idx = it * 256 + tid;
        int r = idx >> 5, c4 = idx & 31;
        float4 v = *(const float4*)(Kp + (size_t)r * DQ + c4 * 4);
        kv_lds[r][c4 * 4 + 0] = f2bf(v.x);
        kv_lds[r][c4 * 4 + 1] = f2bf(v.y);
        kv_lds[r][c4 * 4 + 2] = f2bf(v.z);
        kv_lds[r][c4 * 4 + 3] = f2bf(v.w);
      }
    }
    __syncthreads();

    f32x4 acc[8];
#pragma unroll
    for (int c = 0; c < 8; ++c) acc[c] = (f32x4){0.f, 0.f, 0.f, 0.f};

#pragma unroll
    for (int ks = 0; ks < 4; ++ks) {
#pragma unroll
      for (int c = 0; c < 8; ++c) {
        // B[k][n'] = K[kv0 + c*16 + n'][k] -> lane (qd,n) reads K row c*16+n, 8 contiguous
        short8 bf = *(const short8*)&kv_lds[c * 16 + n][ks * 32 + qd * 8];
        acc[c] = __builtin_amdgcn_mfma_f32_16x16x32_bf16(af[ks], bf, acc[c], 0, 0, 0);
      }
    }

#pragma unroll
    for (int c = 0; c < 8; ++c)
#pragma unroll
      for (int r = 0; r < 4; ++r) acc[c][r] *= scale;

    // online per-row max / sumexp; C/D layout: row = qd*4 + r, col = c*16 + n
#pragma unroll
    for (int r = 0; r < 4; ++r) {
      float t = acc[0][r];
#pragma unroll
      for (int c = 1; c < 8; ++c) t = fmaxf(t, acc[c][r]);
#pragma unroll
      for (int off = 1; off < 16; off <<= 1) t = fmaxf(t, __shfl_xor(t, off, 64));
      float mn = fmaxf(m_run[r], t);
      float s = 0.f;
#pragma unroll
      for (int c = 0; c < 8; ++c) s += __expf(acc[c][r] - mn);
#pragma unroll
      for (int off = 1; off < 16; off <<= 1) s += __shfl_xor(s, off, 64);
      l_run[r] = l_run[r] * __expf(m_run[r] - mn) + s;
      m_run[r] = mn;
    }

    // store raw scaled scores into the weights region (overwritten in phase 2)
#pragma unroll
    for (int c = 0; c < 8; ++c)
#pragma unroll
      for (int r = 0; r < 4; ++r)
        Wb[(size_t)(wv * 16 + qd * 4 + r) * LKVN + kv0 + c * 16 + n] = acc[c][r];
  }

  if (n == 0) {
#pragma unroll
    for (int r = 0; r < 4; ++r) {
      stats_m[wv * 16 + qd * 4 + r] = m_run[r];
      stats_l[wv * 16 + qd * 4 + r] = l_run[r];
    }
  }
  __threadfence();   // drain stores (vmcnt) + L1 coherence before re-reading S
  __syncthreads();

  const int   rl   = wv * 16 + n;           // this lane's Q-row (A-frag m index)
  const float mrow = stats_m[rl];
  const float rinv = 1.0f / stats_l[rl];
  float* Srow = Wb + (size_t)rl * LKVN;

  f32x4 cacc[8];
#pragma unroll
  for (int c = 0; c < 8; ++c) cacc[c] = (f32x4){0.f, 0.f, 0.f, 0.f};

  const short* Vb = Vt + (size_t)b * DVN * LKVN;

  // ---------------- phase 2 ----------------
  for (int kv0 = 0; kv0 < LKVN; kv0 += KT) {
    // prefetch this wave's raw scores for the whole tile (overlaps Vt staging)
    float4 sv[4][2];
#pragma unroll
    for (int ks = 0; ks < 4; ++ks) {
      sv[ks][0] = *(const float4*)(Srow + kv0 + ks * 32 + qd * 8);
      sv[ks][1] = *(const float4*)(Srow + kv0 + ks * 32 + qd * 8 + 4);
    }
    {
      const short* Vp = Vb + kv0;
#pragma unroll
      for (int it = 0; it < 8; ++it) {
        int idx = it * 256 + tid;
        int r = idx >> 4, sg = idx & 15;
        short8 v = *(const short8*)(Vp + (size_t)r * LKVN + sg * 8);
        *(short8*)&kv_lds[r][sg * 8] = v;
      }
    }
    __syncthreads();

#pragma unroll
    for (int ks = 0; ks < 4; ++ks) {
      float p[8];
      p[0] = __expf(sv[ks][0].x - mrow) * rinv;
      p[1] = __expf(sv[ks][0].y - mrow) * rinv;
      p[2] = __expf(sv[ks][0].z - mrow) * rinv;
      p[3] = __expf(sv[ks][0].w - mrow) * rinv;
      p[4] = __expf(sv[ks][1].x - mrow) * rinv;
      p[5] = __expf(sv[ks][1].y - mrow) * rinv;
      p[6] = __expf(sv[ks][1].z - mrow) * rinv;
      p[7] = __expf(sv[ks][1].w - mrow) * rinv;
      float4 w0 = make_float4(p[0], p[1], p[2], p[3]);
      float4 w1 = make_float4(p[4], p[5], p[6], p[7]);
      *(float4*)(Srow + kv0 + ks * 32 + qd * 8)     = w0;   // final weights
      *(float4*)(Srow + kv0 + ks * 32 + qd * 8 + 4) = w1;
      short8 pa;  // p in A-frag layout already: A[m=lane&15][k=qd*8+j]
#pragma unroll
      for (int j = 0; j < 8; ++j) pa[j] = f2bf(p[j]);
#pragma unroll
      for (int c = 0; c < 8; ++c) {
        // B[k][n'] = V[kv0+k][c*16+n'] = Vt_tile[c*16+n'][k], contiguous in k
        short8 bf = *(const short8*)&kv_lds[c * 16 + n][ks * 32 + qd * 8];
        cacc[c] = __builtin_amdgcn_mfma_f32_16x16x32_bf16(pa, bf, cacc[c], 0, 0, 0);
      }
    }
    __syncthreads();  // WAR: done with kv_lds before next tile's staging
  }

  float* Op = O + ((size_t)b * LQN + q0) * DVN;
#pragma unroll
  for (int c = 0; c < 8; ++c)
#pragma unroll
    for (int r = 0; r < 4; ++r)
      Op[(size_t)(wv * 16 + qd * 4 + r) * DVN + c * 16 + n] = cacc[c][r];
}

extern "C" void kernel_launch(void* const* d_in, const int* in_sizes, int n_in,
                              void* d_out, int out_size, void* d_ws, size_t ws_size,
                              hipStream_t stream) {
  const float* Q = (const float*)d_in[0];
  const float* K = (const float*)d_in[1];
  const float* V = (const float*)d_in[2];
  float* W = (float*)d_out;                       // (B, LQ, LKV) attention weights
  float* O = W + (size_t)BB * LQN * LKVN;         // (B, LQ, DV) context
  short* Vt = (short*)d_ws;                       // (B, DV, LKV) bf16, 4 MB

  vtrans_kernel<<<dim3(LKVN / 128, DVN / 32, BB), 256, 0, stream>>>(V, Vt);
  attn_kernel<<<dim3(LQN / QT, BB), 256, 0, stream>>>(Q, K, Vt, W, O);
}

// Round 2
// 224.569 us; speedup vs baseline: 1.3347x; 1.3347x over previous
//
#include <hip/hip_runtime.h>

#define BB    8
#define LQN   2048
#define LKVN  2048
#define DQ    128
#define DVN   128
#define QT    16      // Q rows per block
#define KT    64      // KV tile
#define KSTR  136     // k_lds row stride (bf16 elems): 128 + 8 -> b128 reads conflict-free
#define VSTR  72      // v_lds row stride: 64 + 8
#define PSTR  72
#define NT    (LKVN / KT)   // 32 tiles

typedef short short8 __attribute__((ext_vector_type(8)));
typedef float f32x4  __attribute__((ext_vector_type(4)));

__device__ __forceinline__ short f2bf(float f) {
  unsigned u = __builtin_bit_cast(unsigned, f);
  u += 0x7fffu + ((u >> 16) & 1u);   // round-to-nearest-even
  return (short)(u >> 16);
}

// Q,K fp32 -> bf16 row-major, both tensors in one launch. 2*262144 threads x 8 elems.
__global__ __launch_bounds__(256) void conv_kernel(const float* __restrict__ Q,
                                                   const float* __restrict__ K,
                                                   short* __restrict__ Qb,
                                                   short* __restrict__ Kb) {
  int i = blockIdx.x * 256 + threadIdx.x;
  const float* s; short* d;
  if (i < 262144) { s = Q; d = Qb; }
  else            { s = K; d = Kb; i -= 262144; }
  size_t off = (size_t)i * 8;
  float4 a = *(const float4*)(s + off);
  float4 b = *(const float4*)(s + off + 4);
  short8 o;
  o[0] = f2bf(a.x); o[1] = f2bf(a.y); o[2] = f2bf(a.z); o[3] = f2bf(a.w);
  o[4] = f2bf(b.x); o[5] = f2bf(b.y); o[6] = f2bf(b.z); o[7] = f2bf(b.w);
  *(short8*)(d + off) = o;
}

// V (B, LKV, DV) fp32 -> Vt (B, DV, LKV) bf16
__global__ __launch_bounds__(256) void vtrans_kernel(const float* __restrict__ V,
                                                     short* __restrict__ Vt) {
  __shared__ float tile[128][33];
  const int kv0 = blockIdx.x * 128;
  const int dv0 = blockIdx.y * 32;
  const int b   = blockIdx.z;
  const int tid = threadIdx.x;
  const float* src = V + ((size_t)b * LKVN + kv0) * DVN + dv0;
#pragma unroll
  for (int it = 0; it < 4; ++it) {
    int idx = it * 256 + tid;
    int r = idx >> 3, c4 = idx & 7;
    float4 v = *(const float4*)(src + (size_t)r * DVN + c4 * 4);
    tile[r][c4 * 4 + 0] = v.x;
    tile[r][c4 * 4 + 1] = v.y;
    tile[r][c4 * 4 + 2] = v.z;
    tile[r][c4 * 4 + 3] = v.w;
  }
  __syncthreads();
  short* dst = Vt + ((size_t)b * DVN + dv0) * LKVN + kv0;
#pragma unroll
  for (int it = 0; it < 2; ++it) {
    int idx = it * 256 + tid;
    int row = idx >> 4, ch = idx & 15;
    short8 o;
#pragma unroll
    for (int j = 0; j < 8; ++j) o[j] = f2bf(tile[ch * 8 + j][row]);
    *(short8*)(dst + (size_t)row * LKVN + ch * 8) = o;
  }
}

// One block = 16 Q rows of one batch, 4 waves.
// Phase 1: sweep KV, S = Qb Kb^T (MFMA), accumulate per-lane sum(exp(s)).
// Phase 2: re-sweep, recompute S (bitwise identical), P = exp(s)/l -> W (coalesced-ish),
//          p -> LDS bounce (C/D -> A-frag layout), PV MFMA against LDS-staged Vt.
// Wave w owns KV cols [w*16, w*16+16) for S/P, and DV cols [w*32, w*32+32) for O.
// blockIdx.x & 7 = batch -> XCD-pinned so each batch's bf16 K/V (1.5 MB) stays in one L2.
__global__ __launch_bounds__(256, 4) void attn_kernel(const short* __restrict__ Qb,
                                                      const short* __restrict__ Kb,
                                                      const short* __restrict__ Vt,
                                                      float* __restrict__ W,
                                                      float* __restrict__ O) {
  __shared__ __align__(16) short k_lds[KT][KSTR];    // 17.4 KB  [kv][d]
  __shared__ __align__(16) short v_lds[DVN][VSTR];   // 18.4 KB  [dv][kv]
  __shared__ __align__(16) short p_lds[QT][PSTR];    //  2.3 KB  [q][kv]
  __shared__ float red_l[4][QT];
  __shared__ float stats_r[QT];

  const int tid  = threadIdx.x;
  const int w    = tid >> 6;
  const int lane = tid & 63;
  const int n    = lane & 15;
  const int qd   = lane >> 4;
  const int b    = blockIdx.x & 7;          // batch -> XCD
  const int q0   = (blockIdx.x >> 3) * QT;

  const short* Kbase = Kb + (size_t)b * LKVN * DQ;
  const short* Vbase = Vt + (size_t)b * DVN * LKVN;

  // staging index split (fixed per thread)
  const int kr = tid >> 4, kc = tid & 15;   // K tile: 64 rows x 16 chunks
  const int vr = tid >> 3, vc = tid & 7;    // V tile: 128 rows x 8 chunks

  // Q A-frags, held in registers for both phases
  short8 qf[4];
  {
    const short* Qrow = Qb + ((size_t)b * LQN + q0 + n) * DQ + qd * 8;
#pragma unroll
    for (int ks = 0; ks < 4; ++ks) qf[ks] = *(const short8*)(Qrow + ks * 32);
  }

  const float scale = 0.08838834764831845f;  // 1/sqrt(128)
  float l_part[4] = {0.f, 0.f, 0.f, 0.f};
  short8 kreg[4], vreg[4];

  // ---------------- phase 1: row sums of exp(s) ----------------
#pragma unroll
  for (int it = 0; it < 4; ++it)
    kreg[it] = *(const short8*)(Kbase + (size_t)(kr + it * 16) * DQ + kc * 8);
#pragma unroll
  for (int it = 0; it < 4; ++it)
    *(short8*)&k_lds[kr + it * 16][kc * 8] = kreg[it];

  for (int t = 0; t < NT; ++t) {
    __syncthreads();                       // staged tile visible
    if (t + 1 < NT) {                      // prefetch next tile into regs (latency hidden)
      const short* src = Kbase + (size_t)(t + 1) * KT * DQ;
#pragma unroll
      for (int it = 0; it < 4; ++it)
        kreg[it] = *(const short8*)(src + (size_t)(kr + it * 16) * DQ + kc * 8);
    }
    f32x4 acc = {0.f, 0.f, 0.f, 0.f};
#pragma unroll
    for (int ks = 0; ks < 4; ++ks) {
      short8 bf = *(const short8*)&k_lds[w * 16 + n][ks * 32 + qd * 8];
      acc = __builtin_amdgcn_mfma_f32_16x16x32_bf16(qf[ks], bf, acc, 0, 0, 0);
    }
#pragma unroll
    for (int r = 0; r < 4; ++r) l_part[r] += __expf(acc[r] * scale);
    __syncthreads();                       // all waves done reading k_lds
    if (t + 1 < NT) {
#pragma unroll
      for (int it = 0; it < 4; ++it)
        *(short8*)&k_lds[kr + it * 16][kc * 8] = kreg[it];
    }
  }

#pragma unroll
  for (int r = 0; r < 4; ++r)
#pragma unroll
    for (int off = 1; off < 16; off <<= 1)
      l_part[r] += __shfl_xor(l_part[r], off, 64);
  if (n == 0)
#pragma unroll
    for (int r = 0; r < 4; ++r) red_l[w][qd * 4 + r] = l_part[r];
  __syncthreads();
  if (tid < QT)
    stats_r[tid] = 1.0f / (red_l[0][tid] + red_l[1][tid] + red_l[2][tid] + red_l[3][tid]);
  __syncthreads();
  float rinv[4];
#pragma unroll
  for (int r = 0; r < 4; ++r) rinv[r] = stats_r[qd * 4 + r];

  // ---------------- phase 2: P write + PV ----------------
  f32x4 oacc[2];
  oacc[0] = (f32x4){0.f, 0.f, 0.f, 0.f};
  oacc[1] = (f32x4){0.f, 0.f, 0.f, 0.f};
  float* Wb = W + ((size_t)b * LQN + q0) * LKVN;

#pragma unroll
  for (int it = 0; it < 4; ++it)
    kreg[it] = *(const short8*)(Kbase + (size_t)(kr + it * 16) * DQ + kc * 8);
#pragma unroll
  for (int it = 0; it < 4; ++it)
    vreg[it] = *(const short8*)(Vbase + (size_t)(vr + it * 32) * LKVN + vc * 8);
#pragma unroll
  for (int it = 0; it < 4; ++it)
    *(short8*)&k_lds[kr + it * 16][kc * 8] = kreg[it];
#pragma unroll
  for (int it = 0; it < 4; ++it)
    *(short8*)&v_lds[vr + it * 32][vc * 8] = vreg[it];

  for (int t = 0; t < NT; ++t) {
    const int kv0 = t * KT;
    __syncthreads();                       // A: staged tiles visible, prev PV done
    if (t + 1 < NT) {
      const short* ksrc = Kbase + (size_t)(kv0 + KT) * DQ;
      const short* vsrc = Vbase + kv0 + KT;
#pragma unroll
      for (int it = 0; it < 4; ++it)
        kreg[it] = *(const short8*)(ksrc + (size_t)(kr + it * 16) * DQ + kc * 8);
#pragma unroll
      for (int it = 0; it < 4; ++it)
        vreg[it] = *(const short8*)(vsrc + (size_t)(vr + it * 32) * LKVN + vc * 8);
    }
    f32x4 acc = {0.f, 0.f, 0.f, 0.f};
#pragma unroll
    for (int ks = 0; ks < 4; ++ks) {
      short8 bf = *(const short8*)&k_lds[w * 16 + n][ks * 32 + qd * 8];
      acc = __builtin_amdgcn_mfma_f32_16x16x32_bf16(qf[ks], bf, acc, 0, 0, 0);
    }
    float p[4];
#pragma unroll
    for (int r = 0; r < 4; ++r) p[r] = __expf(acc[r] * scale) * rinv[r];
#pragma unroll
    for (int r = 0; r < 4; ++r)
      Wb[(size_t)(qd * 4 + r) * LKVN + kv0 + w * 16 + n] = p[r];
#pragma unroll
    for (int r = 0; r < 4; ++r) p_lds[qd * 4 + r][w * 16 + n] = f2bf(p[r]);
    __syncthreads();                       // B: p_lds ready
    short8 pa0 = *(const short8*)&p_lds[n][qd * 8];
    short8 pa1 = *(const short8*)&p_lds[n][32 + qd * 8];
#pragma unroll
    for (int c = 0; c < 2; ++c) {
      const int dv = w * 32 + c * 16 + n;
      short8 b0 = *(const short8*)&v_lds[dv][qd * 8];
      short8 b1 = *(const short8*)&v_lds[dv][32 + qd * 8];
      oacc[c] = __builtin_amdgcn_mfma_f32_16x16x32_bf16(pa0, b0, oacc[c], 0, 0, 0);
      oacc[c] = __builtin_amdgcn_mfma_f32_16x16x32_bf16(pa1, b1, oacc[c], 0, 0, 0);
    }
    __syncthreads();                       // C: all readers of k/v/p_lds done
    if (t + 1 < NT) {
#pragma unroll
      for (int it = 0; it < 4; ++it)
        *(short8*)&k_lds[kr + it * 16][kc * 8] = kreg[it];
#pragma unroll
      for (int it = 0; it < 4; ++it)
        *(short8*)&v_lds[vr + it * 32][vc * 8] = vreg[it];
    }
  }

  float* Ob = O + ((size_t)b * LQN + q0) * DVN;
#pragma unroll
  for (int c = 0; c < 2; ++c)
#pragma unroll
    for (int r = 0; r < 4; ++r)
      Ob[(size_t)(qd * 4 + r) * DVN + w * 32 + c * 16 + n] = oacc[c][r];
}

extern "C" void kernel_launch(void* const* d_in, const int* in_sizes, int n_in,
                              void* d_out, int out_size, void* d_ws, size_t ws_size,
                              hipStream_t stream) {
  const float* Q = (const float*)d_in[0];
  const float* K = (const float*)d_in[1];
  const float* V = (const float*)d_in[2];
  float* W = (float*)d_out;                        // (B, LQ, LKV)
  float* O = W + (size_t)BB * LQN * LKVN;          // (B, LQ, DV)
  short* Qb = (short*)d_ws;                        // 4 MB bf16
  short* Kb = Qb + (size_t)BB * LQN * DQ;          // 4 MB
  short* Vt = Kb + (size_t)BB * LKVN * DQ;         // 4 MB (B, DV, LKV)

  conv_kernel<<<2048, 256, 0, stream>>>(Q, K, Qb, Kb);
  vtrans_kernel<<<dim3(LKVN / 128, DVN / 32, BB), 256, 0, stream>>>(V, Vt);
  attn_kernel<<<1024, 256, 0, stream>>>(Qb, Kb, Vt, W, O);
}